// Round 12
// baseline (75.619 us; speedup 1.0000x reference)
//
#include <hip/hip_runtime.h>
#include <math.h>

#define NTOT  16384
#define KNN   50
#define NBINS 5
#define BIGF  1e10f
#define MAXJ  2   // cnt <= 128. cnt ~ Binom(16384,1/256): mean 64, sd 8 -> P(cnt>128) < 1e-13.

// Round 12: TWO nodes per wave (i0 = 2*w, i1 = i0+1), halving the wave count
// and thus all per-wave fixed overhead (batch window, prologue chain, gather
// latency) — the hypothesized residual after rounds 2-11 falsified every
// per-candidate-work theory.
//
// Bounds: batch sorted, cnt <= 128 -> both nodes' same-graph indices lie in
// the shared 256-window [i0-127, i0+128]. 4 loads + 8 ballots give both
// nodes' start/end. Same-graph fast path (P ~ 98.4%) shares the pos gather.
//
// Rank: 32-bit sortable(d2) keys in wave-private LDS; count loop reads
// wave-uniform addresses (same-address broadcast — round-7 win). Pads/self
// hold sortable(BIG) (rank-inert). Ties (~2-3 grid-wide): tie-free <=>
// rank-sum == expected triangular sum (ties -> strictly positive deficit);
// exact rerun with (h<my)||(h==my && k<c) on detect (local k IS the index
// tie-break).
//
// Epilogue: stage per-node 50x{src,dist,rdf5} in LDS, flush coalesced
// (round-11 structure; kept — neutral but not harmful).

__device__ __forceinline__ unsigned int sortable_u32(float d2)
{
    const unsigned int b = __float_as_uint(d2);
    return ((int)b < 0) ? ~b : (b | 0x80000000u);
}

__device__ __forceinline__ float unsortable_f32(unsigned int s)
{
    const unsigned int b = (s & 0x80000000u) ? (s & 0x7fffffffu) : ~s;
    return __uint_as_float(b);
}

__device__ __forceinline__ void stage_and_flush(
    float* __restrict__ out, float* __restrict__ stg,
    const unsigned int (&hi)[MAXJ], const bool (&valid)[MAXJ],
    const int (&rank)[MAXJ], int i, int start, int cnt, int lane)
{
    const float centers[NBINS] = {0.0f, 2.5f, 5.0f, 7.5f, 10.0f};
    const float gamma = 0.08f;              // 1/(2*2.5^2)
    #pragma unroll
    for (int j = 0; j < MAXJ; ++j) {
        if (valid[j] && rank[j] < KNN) {
            const int c = j * 64 + lane;
            const float d = sqrtf(fmaxf(unsortable_f32(hi[j]), 1e-12f));
            const int r = rank[j];
            stg[r]      = (float)(start + c);
            stg[50 + r] = d;
            #pragma unroll
            for (int bb = 0; bb < NBINS; ++bb) {
                const float dd = d - centers[bb];
                stg[100 + r * NBINS + bb] = __expf(-gamma * dd * dd);
            }
        }
    }
    if (cnt <= KNN) {                       // rare: pad slots [cnt-1, KNN)
        const int r = (cnt - 1) + lane;     // at most one slot per lane
        if (r < KNN) {
            const int m = lane;             // m-th smallest BIG-masked index:
            int jj;                         // [0..start) ++ {i} ++ [end..N)
            if (m < start)       jj = m;
            else if (m == start) jj = i;
            else                 jj = (start + cnt) + (m - start - 1);
            stg[r]      = (float)jj;
            stg[50 + r] = 100000.0f;        // sqrt(1e10) exactly
            #pragma unroll
            for (int bb = 0; bb < NBINS; ++bb)
                stg[100 + r * NBINS + bb] = 0.0f;   // exp(-8e8) -> 0
        }
    }
    // coalesced flush: 7 masked stores, all lane-consecutive dwords
    const size_t eb = (size_t)i * KNN;
    if (lane < KNN) {
        out[eb + lane]                          = stg[lane];
        out[(size_t)NTOT * KNN + eb + lane]     = (float)i;
        out[(size_t)2 * NTOT * KNN + eb + lane] = stg[50 + lane];
    }
    float* __restrict__ rbase = out + (size_t)3 * NTOT * KNN + (size_t)i * (KNN * NBINS);
    #pragma unroll
    for (int q = 0; q < 4; ++q) {
        const int idx = lane + 64 * q;
        if (idx < KNN * NBINS)
            rbase[idx] = stg[100 + idx];
    }
}

// full single-node path (used on the rare different-graph waves)
__device__ __forceinline__ void one_node(
    const float* __restrict__ pos, float* __restrict__ out,
    int i, int start, int cnt, int lane,
    unsigned int* __restrict__ keyl, float* __restrict__ stg)
{
    const int J = (cnt + 63) >> 6;
    const float xi = pos[(size_t)i * 3 + 0];
    const float yi = pos[(size_t)i * 3 + 1];
    const float zi = pos[(size_t)i * 3 + 2];
    const float sqi = xi * xi + yi * yi + zi * zi;

    unsigned int hi[MAXJ]; bool valid[MAXJ];
    #pragma unroll
    for (int j = 0; j < MAXJ; ++j) {
        const int c = j * 64 + lane;
        valid[j] = (j < J) && (c < cnt) && ((start + c) != i);
        float d2 = BIGF;
        if (valid[j]) {
            const int idx = start + c;
            const float xj = pos[(size_t)idx * 3 + 0];
            const float yj = pos[(size_t)idx * 3 + 1];
            const float zj = pos[(size_t)idx * 3 + 2];
            const float sqj = xj * xj + yj * yj + zj * zj;
            const float dot = xi * xj + yi * yj + zi * zj;
            d2 = sqi + sqj - 2.0f * dot;    // reference's exact fp32 formula
        }
        hi[j] = sortable_u32(d2);
        keyl[c] = hi[j];
    }

    int rank[MAXJ] = {0, 0};
    const int kpad = (cnt + 7) & ~7;
    const uint4* __restrict__ k4 = reinterpret_cast<const uint4*>(keyl);
    for (int c0 = 0; c0 < kpad; c0 += 8) {
        const uint4 A = k4[(c0 >> 2) + 0];
        const uint4 B = k4[(c0 >> 2) + 1];
        #pragma unroll
        for (int j = 0; j < MAXJ; ++j) {
            rank[j] += (A.x < hi[j]) + (A.y < hi[j]) + (A.z < hi[j]) + (A.w < hi[j])
                     + (B.x < hi[j]) + (B.y < hi[j]) + (B.z < hi[j]) + (B.w < hi[j]);
        }
    }

    // tie detection + exact rerun
    {
        int s = (valid[0] ? rank[0] : 0) + (valid[1] ? rank[1] : 0);
        #pragma unroll
        for (int off = 32; off > 0; off >>= 1) s += __shfl_xor(s, off, 64);
        if (s != (((cnt - 1) * (cnt - 2)) >> 1)) {
            #pragma unroll
            for (int j = 0; j < MAXJ; ++j) {
                if (!valid[j]) continue;
                const int c = j * 64 + lane;
                int r = 0;
                for (int k = 0; k < cnt; ++k) {
                    const unsigned int h = keyl[k];
                    r += (h < hi[j]) || (h == hi[j] && k < c);
                }
                rank[j] = r;
            }
        }
    }
    stage_and_flush(out, stg, hi, valid, rank, i, start, cnt, lane);
}

__global__ __launch_bounds__(256, 4)
void knn_fused2(const float* __restrict__ pos,
                const int*   __restrict__ batch,
                float*       __restrict__ out)
{
    __shared__ unsigned int keys[4][2][128];   // 4 KB, wave-private slices
    __shared__ float        stg [4][2][352];   // 11 KB staging

    const int w    = __builtin_amdgcn_readfirstlane((int)(blockIdx.x * 4 + (threadIdx.x >> 6)));
    const int wv   = threadIdx.x >> 6;
    const int lane = threadIdx.x & 63;
    const int i0 = 2 * w, i1 = i0 + 1;

    const int g0 = batch[i0];               // uniform -> s_load
    const int g1 = batch[i1];

    // shared 256-window [i0-127, i0+128]: position q*64+lane
    const int base = i0 - 127;
    int wq[4]; bool ir[4];
    #pragma unroll
    for (int q = 0; q < 4; ++q) {
        const int j = base + lane + 64 * q;
        ir[q] = (j >= 0) && (j < NTOT);
        wq[q] = batch[min(max(j, 0), NTOT - 1)];
    }
    // node0: window pos of i0 = 127 (q=1, lane 63); node1 at 128 (q=2, lane 0)
    const unsigned long long m00 = __ballot(ir[0] && wq[0] == g0);
    const unsigned long long m01 = __ballot(ir[1] && wq[1] == g0);
    const unsigned long long m02 = __ballot(ir[2] && wq[2] == g0);
    const unsigned long long m03 = __ballot(ir[3] && wq[3] == g0);
    const int c_lo0 = __popcll(m00) + __popcll(m01 & ~(1ull << 63));
    const int c_hi0 = __popcll(m02) + __popcll(m03);
    const int start0 = i0 - c_lo0;
    const int cnt0   = c_lo0 + 1 + c_hi0;

    if (g0 == g1) {
        // shared-graph fast path: start1 == start0, cnt1 == cnt0
        const int S = start0, C = cnt0;
        const int J = (C + 63) >> 6;

        const float x0 = pos[(size_t)i0 * 3 + 0], y0 = pos[(size_t)i0 * 3 + 1], z0 = pos[(size_t)i0 * 3 + 2];
        const float x1 = pos[(size_t)i1 * 3 + 0], y1 = pos[(size_t)i1 * 3 + 1], z1 = pos[(size_t)i1 * 3 + 2];
        const float sq0 = x0 * x0 + y0 * y0 + z0 * z0;
        const float sq1 = x1 * x1 + y1 * y1 + z1 * z1;

        unsigned int h0[MAXJ], h1[MAXJ];
        bool v0[MAXJ], v1[MAXJ];
        #pragma unroll
        for (int j = 0; j < MAXJ; ++j) {
            const int c = j * 64 + lane;
            const bool inb = (j < J) && (c < C);
            const int idx = S + c;
            v0[j] = inb && (idx != i0);
            v1[j] = inb && (idx != i1);
            float d20 = BIGF, d21 = BIGF;
            if (inb) {                       // ONE shared gather for both nodes
                const float xj = pos[(size_t)idx * 3 + 0];
                const float yj = pos[(size_t)idx * 3 + 1];
                const float zj = pos[(size_t)idx * 3 + 2];
                const float sqj = xj * xj + yj * yj + zj * zj;
                if (idx != i0) d20 = sq0 + sqj - 2.0f * (x0 * xj + y0 * yj + z0 * zj);
                if (idx != i1) d21 = sq1 + sqj - 2.0f * (x1 * xj + y1 * yj + z1 * zj);
            }
            h0[j] = sortable_u32(d20);  keys[wv][0][c] = h0[j];
            h1[j] = sortable_u32(d21);  keys[wv][1][c] = h1[j];
        }

        int r0[MAXJ] = {0, 0}, r1[MAXJ] = {0, 0};
        const int kpad = (C + 7) & ~7;
        const uint4* __restrict__ k40 = reinterpret_cast<const uint4*>(&keys[wv][0][0]);
        const uint4* __restrict__ k41 = reinterpret_cast<const uint4*>(&keys[wv][1][0]);
        if (J == 1) {
            int a0 = 0, b0 = 0, a1 = 0, b1 = 0;
            for (int c0 = 0; c0 < kpad; c0 += 8) {
                const uint4 A0 = k40[(c0 >> 2) + 0], B0 = k40[(c0 >> 2) + 1];
                const uint4 A1 = k41[(c0 >> 2) + 0], B1 = k41[(c0 >> 2) + 1];
                a0 += (A0.x < h0[0]) + (A0.y < h0[0]) + (A0.z < h0[0]) + (A0.w < h0[0]);
                b0 += (B0.x < h0[0]) + (B0.y < h0[0]) + (B0.z < h0[0]) + (B0.w < h0[0]);
                a1 += (A1.x < h1[0]) + (A1.y < h1[0]) + (A1.z < h1[0]) + (A1.w < h1[0]);
                b1 += (B1.x < h1[0]) + (B1.y < h1[0]) + (B1.z < h1[0]) + (B1.w < h1[0]);
            }
            r0[0] = a0 + b0;  r1[0] = a1 + b1;
        } else {
            for (int c0 = 0; c0 < kpad; c0 += 8) {
                const uint4 A0 = k40[(c0 >> 2) + 0], B0 = k40[(c0 >> 2) + 1];
                const uint4 A1 = k41[(c0 >> 2) + 0], B1 = k41[(c0 >> 2) + 1];
                #pragma unroll
                for (int j = 0; j < MAXJ; ++j) {
                    r0[j] += (A0.x < h0[j]) + (A0.y < h0[j]) + (A0.z < h0[j]) + (A0.w < h0[j])
                           + (B0.x < h0[j]) + (B0.y < h0[j]) + (B0.z < h0[j]) + (B0.w < h0[j]);
                    r1[j] += (A1.x < h1[j]) + (A1.y < h1[j]) + (A1.z < h1[j]) + (A1.w < h1[j])
                           + (B1.x < h1[j]) + (B1.y < h1[j]) + (B1.z < h1[j]) + (B1.w < h1[j]);
                }
            }
        }

        // combined tie detection: both nodes' rank sums vs 2*T(C)
        {
            int s = (v0[0] ? r0[0] : 0) + (v0[1] ? r0[1] : 0)
                  + (v1[0] ? r1[0] : 0) + (v1[1] ? r1[1] : 0);
            #pragma unroll
            for (int off = 32; off > 0; off >>= 1) s += __shfl_xor(s, off, 64);
            if (s != ((C - 1) * (C - 2))) {  // rare exact-tie path (2x triangular)
                #pragma unroll
                for (int j = 0; j < MAXJ; ++j) {
                    const int c = j * 64 + lane;
                    if (v0[j]) {
                        int r = 0;
                        for (int k = 0; k < C; ++k) {
                            const unsigned int h = keys[wv][0][k];
                            r += (h < h0[j]) || (h == h0[j] && k < c);
                        }
                        r0[j] = r;
                    }
                    if (v1[j]) {
                        int r = 0;
                        for (int k = 0; k < C; ++k) {
                            const unsigned int h = keys[wv][1][k];
                            r += (h < h1[j]) || (h == h1[j] && k < c);
                        }
                        r1[j] = r;
                    }
                }
            }
        }

        stage_and_flush(out, &stg[wv][0][0], h0, v0, r0, i0, S, C, lane);
        stage_and_flush(out, &stg[wv][1][0], h1, v1, r1, i1, S, C, lane);
    } else {
        // rare: consecutive nodes in different graphs (i1 starts its graph)
        const unsigned long long m10 = __ballot(ir[0] && wq[0] == g1);
        const unsigned long long m11 = __ballot(ir[1] && wq[1] == g1);
        const unsigned long long m12 = __ballot(ir[2] && wq[2] == g1);
        const unsigned long long m13 = __ballot(ir[3] && wq[3] == g1);
        const int c_lo1 = __popcll(m10) + __popcll(m11);
        const int c_hi1 = __popcll(m12 & ~1ull) + __popcll(m13);
        const int start1 = i1 - c_lo1;
        const int cnt1   = c_lo1 + 1 + c_hi1;

        one_node(pos, out, i0, start0, cnt0, lane, &keys[wv][0][0], &stg[wv][0][0]);
        one_node(pos, out, i1, start1, cnt1, lane, &keys[wv][1][0], &stg[wv][1][0]);
    }
}

extern "C" void kernel_launch(void* const* d_in, const int* in_sizes, int n_in,
                              void* d_out, int out_size, void* d_ws, size_t ws_size,
                              hipStream_t stream) {
    const float* pos   = (const float*)d_in[0];
    const int*   batch = (const int*)d_in[1];
    float*       out   = (float*)d_out;

    knn_fused2<<<dim3(NTOT / 8), dim3(256), 0, stream>>>(pos, batch, out);
}